// Round 2
// 349.241 us; speedup vs baseline: 1.0072x; 1.0072x over previous
//
#include <hip/hip_runtime.h>
#include <math.h>

#define NPTS 12288
#define DIM 64
#define KNN 85
#define KSEL 86          // 85 neighbors + self
#define SAMPLE 2000
#define SSTRIDE 6        // deterministic sample: idx = 6*p, p in [0,2000)
#define GAMMA 0.5f
#define NT 256           // knn block size (4 waves)
#define WPB 4            // waves per block
#define VIT 12           // float4 dist iterations: 12*256*4 = 12288
#define NV 48            // d2 values per lane; MUST stay fully unrolled
#define VCAP 192         // block-level candidate capacity (~86-95 expected)
#define PT 64            // pearson tile
#define PPITCH 68        // padded LDS pitch (floats)

// ws layout: [0..36] double accumulators; offset 512: cx[N], cy[N], cz[N]
// acc: [0..4] pearson sums; [5..36] spread slots for local-loss partials

__global__ void prep_kernel(const float* __restrict__ coord,
                            float* __restrict__ cx, float* __restrict__ cy,
                            float* __restrict__ cz) {
  int j = blockIdx.x * 256 + threadIdx.x;
  if (j < NPTS) {
    cx[j] = coord[3 * j];
    cy[j] = coord[3 * j + 1];
    cz[j] = coord[3 * j + 2];
  }
}

// exact wave-local radix select (4x8-bit passes) over NV_ vals/lane; values of
// 0xFFFFFFFF are padding and skipped (safe: pool always holds >= want reals).
// h = wave-private 256-bin LDS histogram (wave-internal DS ordering only).
template <int NV_>
__device__ __forceinline__ unsigned wave_select4(const unsigned v[NV_], unsigned want,
                                                 unsigned* h, int lane) {
  unsigned prefix = 0;
  #pragma unroll
  for (int pass = 0; pass < 4; ++pass) {
    const int shift = 24 - 8 * pass;
    const unsigned hmask = pass ? (0xFFFFFFFFu << (shift + 8)) : 0u;
    h[lane] = 0; h[lane + 64] = 0; h[lane + 128] = 0; h[lane + 192] = 0;
    __builtin_amdgcn_wave_barrier();
    #pragma unroll
    for (int t = 0; t < NV_; ++t) {
      unsigned u = v[t];
      if (u != 0xFFFFFFFFu && (u & hmask) == prefix)
        atomicAdd(&h[(u >> shift) & 255u], 1u);
    }
    __builtin_amdgcn_wave_barrier();
    unsigned c0 = h[4 * lane], c1 = h[4 * lane + 1];
    unsigned c2 = h[4 * lane + 2], c3 = h[4 * lane + 3];
    unsigned lt = c0 + c1 + c2 + c3;
    unsigned incl = lt;
    #pragma unroll
    for (int off = 1; off < 64; off <<= 1) {
      unsigned t2 = __shfl_up(incl, off, 64);
      if (lane >= off) incl += t2;
    }
    unsigned excl = incl - lt;
    bool has = (lt > 0) && (excl < want) && (want <= incl);
    unsigned bin = 4 * lane, below = excl, cum = excl;
    if (cum + c0 >= want) { bin = 4 * lane; below = cum; }
    else { cum += c0;
      if (cum + c1 >= want) { bin = 4 * lane + 1; below = cum; }
      else { cum += c1;
        if (cum + c2 >= want) { bin = 4 * lane + 2; below = cum; }
        else { cum += c2; bin = 4 * lane + 3; below = cum; } } }
    unsigned long long bal = __ballot(has);
    int src = __ffsll((unsigned long long)bal) - 1;
    bin = __shfl(bin, src, 64);
    below = __shfl(below, src, 64);
    prefix |= bin << shift;
    want -= below;
  }
  return prefix;
}

__global__ __launch_bounds__(256) void pearson_kernel(
    const float* __restrict__ emb, const float* __restrict__ coord,
    double* __restrict__ acc) {
  __shared__ float EpT[DIM][PPITCH];   // transposed: EpT[k][row]
  __shared__ float EqT[DIM][PPITCH];
  __shared__ float Cp[PT][4];
  __shared__ float Cq[PT][4];
  __shared__ float np_[PT];            // |p|^2 per row
  __shared__ float nq_[PT];            // |q|^2 per row
  __shared__ double wred[4][5];

  const int tid = threadIdx.x;
  const int tx = tid & 15, ty = tid >> 4;
  const int lane = tid & 63, wv = tid >> 6;
  const int p0 = blockIdx.y * PT, q0 = blockIdx.x * PT;

  for (int e = tid; e < PT * DIM; e += 256) {
    int r = e >> 6, k = e & 63;
    int gp = (p0 + r < SAMPLE ? p0 + r : 0) * SSTRIDE;
    int gq = (q0 + r < SAMPLE ? q0 + r : 0) * SSTRIDE;
    EpT[k][r] = emb[(size_t)gp * DIM + k];
    EqT[k][r] = emb[(size_t)gq * DIM + k];
  }
  if (tid < PT) {
    int g = (p0 + tid < SAMPLE ? p0 + tid : 0) * SSTRIDE;
    Cp[tid][0] = coord[3 * g]; Cp[tid][1] = coord[3 * g + 1]; Cp[tid][2] = coord[3 * g + 2];
  } else if (tid < 2 * PT) {
    int r = tid - PT;
    int g = (q0 + r < SAMPLE ? q0 + r : 0) * SSTRIDE;
    Cq[r][0] = coord[3 * g]; Cq[r][1] = coord[3 * g + 1]; Cq[r][2] = coord[3 * g + 2];
  }
  __syncthreads();

  // row norms once per tile (ref uses the same |p|^2+|q|^2-2pq decomposition)
  if (tid < PT) {
    float a = 0.f;
    #pragma unroll 8
    for (int k = 0; k < DIM; ++k) { float v = EpT[k][tid]; a += v * v; }
    np_[tid] = a;
  } else if (tid < 2 * PT) {
    int r = tid - PT;
    float a = 0.f;
    #pragma unroll 8
    for (int k = 0; k < DIM; ++k) { float v = EqT[k][r]; a += v * v; }
    nq_[r] = a;
  }
  __syncthreads();

  // dot-product form: 16 fma/k instead of 16 sub + 16 fma
  float s[4][4] = {};
  #pragma unroll 8
  for (int k = 0; k < DIM; ++k) {
    float4 ep = *(const float4*)&EpT[k][4 * ty];
    float4 eq = *(const float4*)&EqT[k][4 * tx];
    float pa[4] = { ep.x, ep.y, ep.z, ep.w };
    float qa[4] = { eq.x, eq.y, eq.z, eq.w };
    #pragma unroll
    for (int a = 0; a < 4; ++a)
      #pragma unroll
      for (int b = 0; b < 4; ++b)
        s[a][b] += pa[a] * qa[b];
  }

  const float npr[4] = { np_[4 * ty], np_[4 * ty + 1], np_[4 * ty + 2], np_[4 * ty + 3] };
  const float nqr[4] = { nq_[4 * tx], nq_[4 * tx + 1], nq_[4 * tx + 2], nq_[4 * tx + 3] };

  double se = 0, sc = 0, se2 = 0, sc2 = 0, sec = 0;
  #pragma unroll
  for (int a = 0; a < 4; ++a)
    #pragma unroll
    for (int b = 0; b < 4; ++b) {
      int p = p0 + 4 * ty + a, q = q0 + 4 * tx + b;
      if (p < SAMPLE && q < SAMPLE) {
        float sq = fmaxf(npr[a] + nqr[b] - 2.f * s[a][b], 0.f);
        float ed = sqrtf(sq);
        float dx = Cp[4 * ty + a][0] - Cq[4 * tx + b][0];
        float dy = Cp[4 * ty + a][1] - Cq[4 * tx + b][1];
        float dz = Cp[4 * ty + a][2] - Cq[4 * tx + b][2];
        float cd = sqrtf(fmaxf(dx * dx + dy * dy + dz * dz, 0.f));
        se += (double)ed; sc += (double)cd;
        se2 += (double)ed * ed; sc2 += (double)cd * cd;
        sec += (double)ed * cd;
      }
    }

  double vals[5] = { se, sc, se2, sc2, sec };
  #pragma unroll
  for (int v = 0; v < 5; ++v) {
    #pragma unroll
    for (int off = 32; off > 0; off >>= 1) vals[v] += __shfl_xor(vals[v], off, 64);
  }
  if (lane == 0) {
    #pragma unroll
    for (int v = 0; v < 5; ++v) wred[wv][v] = vals[v];
  }
  __syncthreads();
  if (tid < 5) {
    double sm = wred[0][tid] + wred[1][tid] + wred[2][tid] + wred[3][tid];
    atomicAdd(&acc[tid], sm);
  }
}

__global__ __launch_bounds__(NT) void knn_kernel(
    const float* __restrict__ emb, const float* __restrict__ cx,
    const float* __restrict__ cy, const float* __restrict__ cz,
    double* __restrict__ acc) {
  __shared__ unsigned hist[WPB][256];   // 4 KiB: per-wave select scratch
  __shared__ unsigned mset[2 * NT];     // 2 KiB: per-lane {m1,m2}
  __shared__ unsigned vn_u[VCAP];       // block-level candidate list
  __shared__ unsigned short vn_j[VCAP];
  __shared__ unsigned vcnt;

  const int i = blockIdx.x;
  const int tid = threadIdx.x;
  const int lane = tid & 63;
  const int wv = tid >> 6;

  const float qx = cx[i], qy = cy[i], qz = cz[i];
  const float4* CX4 = (const float4*)cx;
  const float4* CY4 = (const float4*)cy;
  const float4* CZ4 = (const float4*)cz;

  // 48 d2 values per thread in VGPRs. FULL unroll is mandatory: constant
  // indices -> register promotion (unroll 1 => scratch spill traffic).
  unsigned d2b[NV];
  #pragma unroll
  for (int it = 0; it < VIT; ++it) {
    int idx = it * NT + tid;
    float4 x4 = CX4[idx], y4 = CY4[idx], z4 = CZ4[idx];
    float dx, dy, dz;
    dx = qx - x4.x; dy = qy - y4.x; dz = qz - z4.x;
    d2b[4 * it + 0] = __float_as_uint(dx * dx + dy * dy + dz * dz);
    dx = qx - x4.y; dy = qy - y4.y; dz = qz - z4.y;
    d2b[4 * it + 1] = __float_as_uint(dx * dx + dy * dy + dz * dz);
    dx = qx - x4.z; dy = qy - y4.z; dz = qz - z4.z;
    d2b[4 * it + 2] = __float_as_uint(dx * dx + dy * dy + dz * dz);
    dx = qx - x4.w; dy = qy - y4.w; dz = qz - z4.w;
    d2b[4 * it + 3] = __float_as_uint(dx * dx + dy * dy + dz * dz);
  }
  const float4 ei4 = ((const float4*)(emb + (size_t)i * DIM))[lane & 15];

  // per-lane two smallest (uint order == nonneg-float order)
  unsigned m1 = 0xFFFFFFFFu, m2 = 0xFFFFFFFFu;
  #pragma unroll
  for (int t = 0; t < NV; ++t) {
    unsigned u = d2b[t];
    unsigned hi = u > m1 ? u : m1;
    m1 = u < m1 ? u : m1;
    m2 = hi < m2 ? hi : m2;
  }
  mset[2 * tid] = m1;
  mset[2 * tid + 1] = m2;
  if (tid == 0) vcnt = 0;
  __syncthreads();   // barrier 1: m-set + vcnt=0 visible

  // ---- stage 1: T = exact 86th smallest of the 512-value m-set.
  // Safety: the 86 m-values <= T are >=86 distinct d2 elements, so
  // T >= global 86th. Tightness: the 86 global-smallest spread ~0.34/lane
  // over 256 lanes, so nearly all appear in the m-set -> count(<=T) ~ 86-95.
  // Every wave computes T redundantly (parallel; no broadcast barrier).
  unsigned mv[8];
  {
    const uint4* M4 = (const uint4*)&mset[8 * lane];
    uint4 a = M4[0], b = M4[1];
    mv[0] = a.x; mv[1] = a.y; mv[2] = a.z; mv[3] = a.w;
    mv[4] = b.x; mv[5] = b.y; mv[6] = b.z; mv[7] = b.w;
  }
  const unsigned T = wave_select4<8>(mv, KSEL, hist[wv], lane);

  // ---- stage 2: append all candidates u <= T to the block list ----
  #pragma unroll
  for (int t = 0; t < NV; ++t) {
    unsigned u = d2b[t];
    if (u <= T) {
      unsigned pos = atomicAdd(&vcnt, 1u);
      if (pos < VCAP) {
        vn_u[pos] = u;
        vn_j[pos] = (unsigned short)(4 * ((t >> 2) * NT + tid) + (t & 3));
      }
    }
  }
  __syncthreads();   // barrier 2: candidate list visible
  const int tot = (int)(vcnt < VCAP ? vcnt : VCAP);

  // ---- stage 3: exact global 86th among candidates (redundant per wave) ----
  unsigned cv[3];
  cv[0] = (lane < tot) ? vn_u[lane] : 0xFFFFFFFFu;
  cv[1] = (lane + 64 < tot) ? vn_u[lane + 64] : 0xFFFFFFFFu;
  cv[2] = (lane + 128 < tot) ? vn_u[lane + 128] : 0xFFFFFFFFu;
  const unsigned thr = wave_select4<3>(cv, KSEL, hist[wv], lane);

  // ---- loss: 16 candidates per block-iteration, inline validity filter ----
  const int q = lane >> 4;
  const int l16 = lane & 15;
  float lsum = 0.f;
  for (int base = wv * 4; base < tot; base += 16) {   // wave-uniform trip count
    int idx = base + q;
    bool valid = idx < tot;
    unsigned u = 0; int j = 0;
    if (valid) {
      u = vn_u[idx]; j = (int)vn_j[idx];
      valid = (u <= thr) && (j != i);
    }
    float s = 0.f;
    if (valid) {
      float4 e4 = ((const float4*)(emb + (size_t)j * DIM))[l16];
      float d0 = ei4.x - e4.x, d1 = ei4.y - e4.y;
      float d2 = ei4.z - e4.z, d3 = ei4.w - e4.w;
      s = d0 * d0 + d1 * d1 + d2 * d2 + d3 * d3;
    }
    s += __shfl_xor(s, 1, 64);
    s += __shfl_xor(s, 2, 64);
    s += __shfl_xor(s, 4, 64);
    s += __shfl_xor(s, 8, 64);
    if (valid && l16 == 0) {
      float td = sqrtf(__uint_as_float(u));
      float pd = sqrtf(fmaxf(s, 0.f));
      float diff = pd - td;
      lsum += diff * diff * expf(-GAMMA * td);
    }
  }
  #pragma unroll
  for (int off = 32; off > 0; off >>= 1) lsum += __shfl_xor(lsum, off, 64);
  if (lane == 0) atomicAdd(&acc[5 + (blockIdx.x & 7) * 4 + wv], (double)lsum);
}

__global__ void finalize_kernel(const double* __restrict__ acc,
                                float* __restrict__ out) {
  double M = (double)SAMPLE * (double)SAMPLE;
  double med = acc[0] / M, mcd = acc[1] / M;
  double ve = acc[2] / M - med * med;
  double vc = acc[3] / M - mcd * mcd;
  double es = sqrt(ve + 1e-8);
  double cs = sqrt(vc + 1e-8);
  double cov = acc[4] / M - med * mcd;
  double pearson = cov / (es * cs + 1e-8);
  double lsum = 0.0;
  for (int s = 5; s < 37; ++s) lsum += acc[s];
  double local = lsum / ((double)NPTS * (double)KNN);
  out[0] = (float)((1.0 - pearson) + 0.5 * local);
}

extern "C" void kernel_launch(void* const* d_in, const int* in_sizes, int n_in,
                              void* d_out, int out_size, void* d_ws, size_t ws_size,
                              hipStream_t stream) {
  const float* emb = (const float*)d_in[0];    // (12288, 64) f32
  const float* coord = (const float*)d_in[1];  // (12288, 3) f32
  double* acc = (double*)d_ws;
  float* cx = (float*)((char*)d_ws + 512);     // 16B-aligned SoA coords
  float* cy = cx + NPTS;
  float* cz = cy + NPTS;

  hipMemsetAsync(d_ws, 0, 37 * sizeof(double), stream);

  prep_kernel<<<(NPTS + 255) / 256, 256, 0, stream>>>(coord, cx, cy, cz);

  pearson_kernel<<<dim3((SAMPLE + PT - 1) / PT, (SAMPLE + PT - 1) / PT), 256, 0, stream>>>(
      emb, coord, acc);

  knn_kernel<<<NPTS, NT, 0, stream>>>(emb, cx, cy, cz, acc);

  finalize_kernel<<<1, 1, 0, stream>>>(acc, (float*)d_out);
}

// Round 3
// 325.671 us; speedup vs baseline: 1.0801x; 1.0724x over previous
//
#include <hip/hip_runtime.h>
#include <math.h>

#define NPTS 12288
#define DIM 64
#define KNN 85
#define KSEL 86          // 85 neighbors + self
#define SAMPLE 2000
#define SSTRIDE 6        // deterministic sample: idx = 6*p, p in [0,2000)
#define GAMMA 0.5f
#define NT 256           // block size (4 waves)
#define WPB 4            // waves per block
#define VIT 12           // float4 dist iterations: 12*256*4 = 12288
#define NV 48            // d2 values per lane; MUST stay fully unrolled
#define VCAP 224         // block-level candidate capacity (~100-130 expected)
#define PT 64            // pearson tile
#define PPITCH 68        // padded LDS pitch (floats)
#define PBLK 1024        // pearson blocks: (2000/64 ceil)=32 -> 32x32

// ws layout: [0..36] double accumulators; offset 512: cx[N], cy[N], cz[N]
// acc: [0..4] pearson sums; [5..36] spread slots for local-loss partials

struct PearsonS {
  float EpT[DIM][PPITCH];   // transposed: EpT[k][row]
  float EqT[DIM][PPITCH];
  float Cp[PT][4];
  float Cq[PT][4];
  float np_[PT];
  float nq_[PT];
  double wred[4][5];
};
struct KnnS {
  unsigned hist[WPB][264];          // 264 pitch: wave w's bin b -> bank (8w+b)%32
  unsigned mset[2 * NT];            // per-lane {m1,m2}
  unsigned bmax[WPB];               // per-wave max of m2
  unsigned long long vkey[VCAP + 8]; // (u<<14)|j candidate keys
  unsigned char keep[VCAP + 8];
  unsigned vcnt;
};
union SharedU { PearsonS p; KnnS k; };

__global__ void prep_kernel(const float* __restrict__ coord,
                            float* __restrict__ cx, float* __restrict__ cy,
                            float* __restrict__ cz) {
  int j = blockIdx.x * 256 + threadIdx.x;
  if (j < NPTS) {
    cx[j] = coord[3 * j];
    cy[j] = coord[3 * j + 1];
    cz[j] = coord[3 * j + 2];
  }
}

__device__ __forceinline__ void pearson_body(
    SharedU& sh, const float* __restrict__ emb, const float* __restrict__ coord,
    double* __restrict__ acc) {
  const int tid = threadIdx.x;
  const int tx = tid & 15, ty = tid >> 4;
  const int lane = tid & 63, wv = tid >> 6;
  const int pb = blockIdx.x;
  const int p0 = (pb >> 5) * PT, q0 = (pb & 31) * PT;

  for (int e = tid; e < PT * DIM; e += 256) {
    int r = e >> 6, k = e & 63;
    int gp = (p0 + r < SAMPLE ? p0 + r : 0) * SSTRIDE;
    int gq = (q0 + r < SAMPLE ? q0 + r : 0) * SSTRIDE;
    sh.p.EpT[k][r] = emb[(size_t)gp * DIM + k];
    sh.p.EqT[k][r] = emb[(size_t)gq * DIM + k];
  }
  if (tid < PT) {
    int g = (p0 + tid < SAMPLE ? p0 + tid : 0) * SSTRIDE;
    sh.p.Cp[tid][0] = coord[3 * g]; sh.p.Cp[tid][1] = coord[3 * g + 1]; sh.p.Cp[tid][2] = coord[3 * g + 2];
  } else if (tid < 2 * PT) {
    int r = tid - PT;
    int g = (q0 + r < SAMPLE ? q0 + r : 0) * SSTRIDE;
    sh.p.Cq[r][0] = coord[3 * g]; sh.p.Cq[r][1] = coord[3 * g + 1]; sh.p.Cq[r][2] = coord[3 * g + 2];
  }
  __syncthreads();

  // row norms once per tile (ref uses the same |p|^2+|q|^2-2pq decomposition)
  if (tid < PT) {
    float a = 0.f;
    #pragma unroll 8
    for (int k = 0; k < DIM; ++k) { float v = sh.p.EpT[k][tid]; a += v * v; }
    sh.p.np_[tid] = a;
  } else if (tid < 2 * PT) {
    int r = tid - PT;
    float a = 0.f;
    #pragma unroll 8
    for (int k = 0; k < DIM; ++k) { float v = sh.p.EqT[k][r]; a += v * v; }
    sh.p.nq_[r] = a;
  }
  __syncthreads();

  float s[4][4] = {};
  #pragma unroll 8
  for (int k = 0; k < DIM; ++k) {
    float4 ep = *(const float4*)&sh.p.EpT[k][4 * ty];
    float4 eq = *(const float4*)&sh.p.EqT[k][4 * tx];
    float pa[4] = { ep.x, ep.y, ep.z, ep.w };
    float qa[4] = { eq.x, eq.y, eq.z, eq.w };
    #pragma unroll
    for (int a = 0; a < 4; ++a)
      #pragma unroll
      for (int b = 0; b < 4; ++b)
        s[a][b] += pa[a] * qa[b];
  }

  const float npr[4] = { sh.p.np_[4 * ty], sh.p.np_[4 * ty + 1], sh.p.np_[4 * ty + 2], sh.p.np_[4 * ty + 3] };
  const float nqr[4] = { sh.p.nq_[4 * tx], sh.p.nq_[4 * tx + 1], sh.p.nq_[4 * tx + 2], sh.p.nq_[4 * tx + 3] };

  double se = 0, sc = 0, se2 = 0, sc2 = 0, sec = 0;
  #pragma unroll
  for (int a = 0; a < 4; ++a)
    #pragma unroll
    for (int b = 0; b < 4; ++b) {
      int p = p0 + 4 * ty + a, q = q0 + 4 * tx + b;
      if (p < SAMPLE && q < SAMPLE) {
        float sq = fmaxf(npr[a] + nqr[b] - 2.f * s[a][b], 0.f);
        float ed = sqrtf(sq);
        float dx = sh.p.Cp[4 * ty + a][0] - sh.p.Cq[4 * tx + b][0];
        float dy = sh.p.Cp[4 * ty + a][1] - sh.p.Cq[4 * tx + b][1];
        float dz = sh.p.Cp[4 * ty + a][2] - sh.p.Cq[4 * tx + b][2];
        float cd = sqrtf(fmaxf(dx * dx + dy * dy + dz * dz, 0.f));
        se += (double)ed; sc += (double)cd;
        se2 += (double)ed * ed; sc2 += (double)cd * cd;
        sec += (double)ed * cd;
      }
    }

  double vals[5] = { se, sc, se2, sc2, sec };
  #pragma unroll
  for (int v = 0; v < 5; ++v) {
    #pragma unroll
    for (int off = 32; off > 0; off >>= 1) vals[v] += __shfl_xor(vals[v], off, 64);
  }
  if (lane == 0) {
    #pragma unroll
    for (int v = 0; v < 5; ++v) sh.p.wred[wv][v] = vals[v];
  }
  __syncthreads();
  if (tid < 5) {
    double sm = sh.p.wred[0][tid] + sh.p.wred[1][tid] + sh.p.wred[2][tid] + sh.p.wred[3][tid];
    atomicAdd(&acc[tid], sm);
  }
}

__device__ __forceinline__ void knn_body(
    SharedU& sh, const float* __restrict__ emb, const float* __restrict__ cx,
    const float* __restrict__ cy, const float* __restrict__ cz,
    double* __restrict__ acc) {
  const int i = blockIdx.x - PBLK;
  const int tid = threadIdx.x;
  const int lane = tid & 63;
  const int wv = tid >> 6;

  const float qx = cx[i], qy = cy[i], qz = cz[i];
  const float4* CX4 = (const float4*)cx;
  const float4* CY4 = (const float4*)cy;
  const float4* CZ4 = (const float4*)cz;

  // 48 d2 values per thread in VGPRs. FULL unroll is mandatory: constant
  // indices -> register promotion (unroll 1 => scratch spill traffic).
  unsigned d2b[NV];
  #pragma unroll
  for (int it = 0; it < VIT; ++it) {
    int idx = it * NT + tid;
    float4 x4 = CX4[idx], y4 = CY4[idx], z4 = CZ4[idx];
    float dx, dy, dz;
    dx = qx - x4.x; dy = qy - y4.x; dz = qz - z4.x;
    d2b[4 * it + 0] = __float_as_uint(dx * dx + dy * dy + dz * dz);
    dx = qx - x4.y; dy = qy - y4.y; dz = qz - z4.y;
    d2b[4 * it + 1] = __float_as_uint(dx * dx + dy * dy + dz * dz);
    dx = qx - x4.z; dy = qy - y4.z; dz = qz - z4.z;
    d2b[4 * it + 2] = __float_as_uint(dx * dx + dy * dy + dz * dz);
    dx = qx - x4.w; dy = qy - y4.w; dz = qz - z4.w;
    d2b[4 * it + 3] = __float_as_uint(dx * dx + dy * dy + dz * dz);
  }
  const float4 ei4 = ((const float4*)(emb + (size_t)i * DIM))[lane & 15];

  // per-lane two smallest (uint order == nonneg-float order)
  unsigned m1 = 0xFFFFFFFFu, m2 = 0xFFFFFFFFu;
  #pragma unroll
  for (int t = 0; t < NV; ++t) {
    unsigned u = d2b[t];
    unsigned hi = u > m1 ? u : m1;
    m1 = u < m1 ? u : m1;
    m2 = hi < m2 ? hi : m2;
  }
  // wave-max of m2 (all 128 m-values of this wave are <= it)
  unsigned M2w = m2;
  #pragma unroll
  for (int off = 32; off > 0; off >>= 1) {
    unsigned t2 = __shfl_xor((int)M2w, off, 64);
    M2w = t2 > M2w ? t2 : M2w;
  }
  if (lane == 0) sh.k.bmax[wv] = M2w;
  sh.k.mset[2 * tid] = m1;
  sh.k.mset[2 * tid + 1] = m2;
  if (tid == 0) sh.k.vcnt = 0;
  __syncthreads();   // barrier 1: m-set + bmax + vcnt=0 visible

  // ---- stage 1: T >= 86th-smallest of the 512-value m-set, via ONE
  // linear-binned histogram pass (uniform bins => no same-address atomic
  // storm, unlike radix pass-0 on the exponent byte). B = min over waves of
  // (wave-max m2): the minimizing wave alone contributes 128 m-values <= B,
  // so cum reaches 86 strictly below bin 255. T = upper edge of crossing bin
  // => count(m <= T) >= 86 => >=86 distinct d2 <= T => T >= global 86th.
  const unsigned b0 = sh.k.bmax[0], b1 = sh.k.bmax[1];
  const unsigned b2_ = sh.k.bmax[2], b3 = sh.k.bmax[3];
  unsigned Bu = b0 < b1 ? b0 : b1;
  unsigned Bu2 = b2_ < b3 ? b2_ : b3;
  Bu = Bu < Bu2 ? Bu : Bu2;
  const float Bf = fmaxf(__uint_as_float(Bu), 1e-30f);
  const float sbin = 256.0f / Bf;

  unsigned* h = sh.k.hist[wv];      // redundant per wave; padded rows
  h[lane] = 0; h[lane + 64] = 0; h[lane + 128] = 0; h[lane + 192] = 0;
  __builtin_amdgcn_wave_barrier();
  {
    const uint4* M4 = (const uint4*)&sh.k.mset[8 * lane];
    uint4 a = M4[0], b = M4[1];
    unsigned mv[8] = { a.x, a.y, a.z, a.w, b.x, b.y, b.z, b.w };
    #pragma unroll
    for (int t = 0; t < 8; ++t) {
      int bb = (int)(__uint_as_float(mv[t]) * sbin);
      bb = bb > 255 ? 255 : bb;
      atomicAdd(&h[bb], 1u);
    }
  }
  __builtin_amdgcn_wave_barrier();
  unsigned c0 = h[4 * lane], c1 = h[4 * lane + 1];
  unsigned c2 = h[4 * lane + 2], c3 = h[4 * lane + 3];
  unsigned lt = c0 + c1 + c2 + c3;
  unsigned incl = lt;
  #pragma unroll
  for (int off = 1; off < 64; off <<= 1) {
    unsigned t2 = __shfl_up(incl, off, 64);
    if (lane >= off) incl += t2;
  }
  unsigned excl = incl - lt;
  bool has = (lt > 0) && (excl < KSEL) && (KSEL <= incl);
  unsigned bin = 4 * lane, cum = excl;
  if (cum + c0 >= KSEL) { bin = 4 * lane; }
  else { cum += c0;
    if (cum + c1 >= KSEL) { bin = 4 * lane + 1; }
    else { cum += c1;
      if (cum + c2 >= KSEL) { bin = 4 * lane + 2; }
      else { bin = 4 * lane + 3; } } }
  unsigned long long bal = __ballot(has);
  int src = __ffsll((unsigned long long)bal) - 1;
  unsigned bsel = __shfl((int)bin, src, 64);
  float Uf = (float)(bsel + 1) * (Bf * (1.0f / 256.0f)) * 1.000002f;
  const unsigned T = __float_as_uint(Uf);

  // ---- stage 2: append candidates u <= T as 64-bit keys (u<<14)|j ----
  #pragma unroll
  for (int t = 0; t < NV; ++t) {
    unsigned u = d2b[t];
    if (u <= T) {
      unsigned pos = atomicAdd(&sh.k.vcnt, 1u);
      if (pos < VCAP) {
        unsigned pj = (unsigned)(4 * ((t >> 2) * NT + tid) + (t & 3));
        sh.k.vkey[pos] = ((unsigned long long)u << 14) | pj;
      }
    }
  }
  __syncthreads();   // barrier 2: candidate list visible
  const unsigned vc = sh.k.vcnt;
  const int tot = (int)(vc < VCAP ? vc : VCAP);

  // ---- stage 3: exact top-86 via rank counting (no atomics, exact jax
  // top_k tie semantics: smaller distance first, then smaller index) ----
  if (tid < tot) {
    const unsigned long long kt = sh.k.vkey[tid];
    int rank = 0;
    for (int k = 0; k < tot; ++k) rank += (sh.k.vkey[k] < kt) ? 1 : 0;
    const unsigned jj = (unsigned)(kt & 0x3FFFu);
    sh.k.keep[tid] = (rank < KSEL && jj != (unsigned)i) ? 1 : 0;
  }
  __syncthreads();   // barrier 3: keep flags visible

  // ---- loss: 16 candidates per block-iteration, keep-flag filter ----
  const int q = lane >> 4;
  const int l16 = lane & 15;
  float lsum = 0.f;
  for (int base = wv * 4; base < tot; base += 16) {   // wave-uniform trip count
    int idx = base + q;
    bool valid = false;
    unsigned u = 0; int j = 0;
    if (idx < tot && sh.k.keep[idx]) {
      unsigned long long kk = sh.k.vkey[idx];
      u = (unsigned)(kk >> 14);
      j = (int)(kk & 0x3FFFu);
      valid = true;
    }
    float s = 0.f;
    if (valid) {
      float4 e4 = ((const float4*)(emb + (size_t)j * DIM))[l16];
      float d0 = ei4.x - e4.x, d1 = ei4.y - e4.y;
      float d2 = ei4.z - e4.z, d3 = ei4.w - e4.w;
      s = d0 * d0 + d1 * d1 + d2 * d2 + d3 * d3;
    }
    s += __shfl_xor(s, 1, 64);
    s += __shfl_xor(s, 2, 64);
    s += __shfl_xor(s, 4, 64);
    s += __shfl_xor(s, 8, 64);
    if (valid && l16 == 0) {
      float td = sqrtf(__uint_as_float(u));
      float pd = sqrtf(fmaxf(s, 0.f));
      float diff = pd - td;
      lsum += diff * diff * expf(-GAMMA * td);
    }
  }
  #pragma unroll
  for (int off = 32; off > 0; off >>= 1) lsum += __shfl_xor(lsum, off, 64);
  if (lane == 0) atomicAdd(&acc[5 + (i & 7) * 4 + wv], (double)lsum);
}

__global__ __launch_bounds__(NT) void fused_kernel(
    const float* __restrict__ emb, const float* __restrict__ coord,
    const float* __restrict__ cx, const float* __restrict__ cy,
    const float* __restrict__ cz, double* __restrict__ acc) {
  __shared__ SharedU sh;
  if (blockIdx.x < PBLK) {
    pearson_body(sh, emb, coord, acc);
  } else {
    knn_body(sh, emb, cx, cy, cz, acc);
  }
}

__global__ void finalize_kernel(const double* __restrict__ acc,
                                float* __restrict__ out) {
  double M = (double)SAMPLE * (double)SAMPLE;
  double med = acc[0] / M, mcd = acc[1] / M;
  double ve = acc[2] / M - med * med;
  double vc = acc[3] / M - mcd * mcd;
  double es = sqrt(ve + 1e-8);
  double cs = sqrt(vc + 1e-8);
  double cov = acc[4] / M - med * mcd;
  double pearson = cov / (es * cs + 1e-8);
  double lsum = 0.0;
  for (int s = 5; s < 37; ++s) lsum += acc[s];
  double local = lsum / ((double)NPTS * (double)KNN);
  out[0] = (float)((1.0 - pearson) + 0.5 * local);
}

extern "C" void kernel_launch(void* const* d_in, const int* in_sizes, int n_in,
                              void* d_out, int out_size, void* d_ws, size_t ws_size,
                              hipStream_t stream) {
  const float* emb = (const float*)d_in[0];    // (12288, 64) f32
  const float* coord = (const float*)d_in[1];  // (12288, 3) f32
  double* acc = (double*)d_ws;
  float* cx = (float*)((char*)d_ws + 512);     // 16B-aligned SoA coords
  float* cy = cx + NPTS;
  float* cz = cy + NPTS;

  hipMemsetAsync(d_ws, 0, 37 * sizeof(double), stream);

  prep_kernel<<<(NPTS + 255) / 256, 256, 0, stream>>>(coord, cx, cy, cz);

  fused_kernel<<<PBLK + NPTS, NT, 0, stream>>>(emb, coord, cx, cy, cz, acc);

  finalize_kernel<<<1, 1, 0, stream>>>(acc, (float*)d_out);
}